// Round 11
// baseline (1179.592 us; speedup 1.0000x reference)
//
#include <hip/hip_runtime.h>
#include <stdint.h>
#include <stddef.h>

#define BATCH 512
#define NQ    65536
#define DIM   768
#define DIM2  1536
#define CONVB 2048

typedef __attribute__((ext_vector_type(4))) float f32x4;
typedef __attribute__((ext_vector_type(4))) unsigned short u16x4;
typedef __attribute__((ext_vector_type(8))) unsigned short u16x8;
typedef __attribute__((ext_vector_type(8))) __bf16 bf16x8;

// ---------- fp32 <-> bf16 (round-to-nearest-even) ----------
static __device__ __forceinline__ unsigned short f2bf(float x){
    unsigned int u = __float_as_uint(x);
    unsigned int r = ((u >> 16) & 1u) + 0x7fffu;
    return (unsigned short)((u + r) >> 16);
}
static __device__ __forceinline__ float bf2f(unsigned short h){
    return __uint_as_float(((unsigned int)h) << 16);
}

// ---------- top-2 tracking ----------
struct T2 { float v1, v2; int i1, i2; };
static __device__ __forceinline__ void t2_add(T2& t, float v, int i){
    if (v > t.v1 || (v == t.v1 && i < t.i1)) { t.v2 = t.v1; t.i2 = t.i1; t.v1 = v; t.i1 = i; }
    else if (v > t.v2 || (v == t.v2 && i < t.i2)) { t.v2 = v; t.i2 = i; }
}
static __device__ __forceinline__ T2 t2_init(){ T2 t; t.v1 = -3.4e38f; t.v2 = -3.4e38f; t.i1 = 0x7fffffff; t.i2 = 0x7fffffff; return t; }

// ---------- prep_all: qtxt->bf16 + feature prep + weight transpose ----------
// blocks [0, CONVB): grid-stride qtxt -> Bt_hi (bf16). qimg conversion and all fp32
//   new_queue passthroughs moved into the big GEMMs' convert waves.
// blocks [CONVB, +2*BATCH): L2-normalize feats, split hi/lo, out2/out3 rows 0..511 exact.
// remaining 2304: transpose W_diff/W_comb -> [768][1536] fp32.
__global__ __launch_bounds__(256) void prep_all(
    const float* __restrict__ img, const float* __restrict__ txt,
    const float* __restrict__ qtxt,
    const float* __restrict__ Wd, const float* __restrict__ Wc,
    unsigned short* __restrict__ bthi,
    float* __restrict__ img_f, float* __restrict__ txt_f,
    unsigned short* __restrict__ X2hi, unsigned short* __restrict__ X2lo,
    unsigned short* __restrict__ X1hi, unsigned short* __restrict__ X1lo,
    float* __restrict__ out2, float* __restrict__ out3,
    float* __restrict__ Td, float* __restrict__ Tc)
{
    __shared__ float tbuf[32][33];
    __shared__ float red[4];
    const int b = blockIdx.x;
    if (b < CONVB){
        const size_t n4 = (size_t)NQ * DIM / 4;
        for (size_t i = (size_t)b * 256 + threadIdx.x; i < n4; i += (size_t)CONVB * 256){
            f32x4 v = ((const f32x4*)qtxt)[i];
            u16x4 h;
            #pragma unroll
            for (int j = 0; j < 4; j++) h[j] = f2bf(v[j]);
            *(u16x4*)(bthi + 4*i) = h;
        }
    } else if (b < CONVB + 2 * BATCH){
        const int b2 = b - CONVB;
        const bool isimg = (b2 < BATCH);
        const int row = isimg ? b2 : b2 - BATCH;
        const float* src = (isimg ? img : txt) + (size_t)row * DIM;
        float v[3];
        float ss = 0.f;
        #pragma unroll
        for (int i = 0; i < 3; i++){ v[i] = src[threadIdx.x + i*256]; ss += v[i]*v[i]; }
        #pragma unroll
        for (int m = 1; m < 64; m <<= 1) ss += __shfl_xor(ss, m);
        if ((threadIdx.x & 63) == 0) red[threadIdx.x >> 6] = ss;
        __syncthreads();
        float tot = red[0] + red[1] + red[2] + red[3];
        float scale = 1.0f / fmaxf(sqrtf(tot), 1e-12f);
        float* fdst = (isimg ? img_f : txt_f) + (size_t)row * DIM;
        float* odst = (isimg ? out2  : out3 ) + (size_t)row * DIM;
        unsigned short* hid = (isimg ? X2hi : X1hi) + (size_t)row * DIM2;
        unsigned short* lod = (isimg ? X2lo : X1lo) + (size_t)row * DIM2;
        #pragma unroll
        for (int i = 0; i < 3; i++){
            int c = threadIdx.x + i*256;
            float y = v[i] * scale;
            fdst[c] = y; odst[c] = y;
            unsigned short h = f2bf(y);
            hid[c] = h; lod[c] = f2bf(y - bf2f(h));
        }
    } else {
        int t = b - CONVB - 2 * BATCH;           // 0..2303
        const int z = t / 1152; t -= z * 1152;    // 1152 = 24 * 48
        const int x = t % 24, y = t / 24;
        const float* W = z ? Wc : Wd;
        float*       T = z ? Tc : Td;
        const int x0 = x * 32, y0 = y * 32;
        const int tx = threadIdx.x & 31, ty = threadIdx.x >> 5;
        #pragma unroll
        for (int i = 0; i < 32; i += 8)
            tbuf[ty + i][tx] = W[(size_t)(y0 + ty + i) * DIM + x0 + tx];
        __syncthreads();
        #pragma unroll
        for (int i = 0; i < 32; i += 8)
            T[(size_t)(x0 + ty + i) * DIM2 + y0 + tx] = tbuf[tx][ty + i];
    }
}

#define EPI_TOP2      0
#define EPI_BIAS_RELU 1
#define EPI_BIAS      2
#define EPI_SCALE     3

// ---------- big GEMM: 8-phase schedule + producer convert waves ----------
// Waves 0..7: R10's verified GEMM K-loop, byte-identical (vmcnt is per-wave, so the
// convert waves do not disturb the counted-vmcnt ledger).
// Waves 8..9: convert role. Mirrors the GEMM barrier sequence EXACTLY:
//   GEMM arrivals = 1 (prologue) + nk*4*2 (main, nk=12) + (TOP2 ? 1 : 0) = 98 / 97.
//   Convert arrivals = 1 + 48*2 + (TOP2 ? 1 : 0).
// Work: 12,582,912 f32x4 chunks = 192 sweeps of 65536 (512 blk x 2 waves x 64 lanes)
//   = exactly 4 sweeps per phase-slot (48 slots). Pipelined: issue slot p+1, flush p.
// K2 (TOP2): cv_src=qimg -> cv_bf=Bi_hi + cv_fp=out2 (rows>=512, NT).
// K6 (SCALE): cv_src=qtxt -> cv_fp=out3 (rows>=512, NT), cv_bf=null.
template<int EPI>
__global__ __launch_bounds__(640, 1) void gemm_big(
    const unsigned short* __restrict__ Ahi, const unsigned short* __restrict__ Alo, int lda,
    const unsigned short* __restrict__ Bhi, const unsigned short* __restrict__ Blo, int ldb,
    int K, int Nout,
    float* __restrict__ outp, const float* __restrict__ scale_ptr, int Mtot,
    const float* __restrict__ cv_src, unsigned short* __restrict__ cv_bf,
    float* __restrict__ cv_fp)
{
    constexpr int STG = 512;            // GEMM staging thread count
    constexpr int KS = 64;
    constexpr int HT = 16384;           // half-tile bytes: 128 rows x 128B
    constexpr int BUF = 4 * HT;         // 64 KiB per K-step
    __shared__ __align__(16) char lds[2 * BUF];   // 128 KiB

    const int tid = threadIdx.x, lane = tid & 63, wid = tid >> 6;
    const int nk = K / KS;   // 12

    if (wid < 8){
        const int wm = wid >> 2, wn = wid & 3;
        const int lr = lane & 15, lg = lane >> 4;
        const int id = blockIdx.x;
        const int l  = (id & 7) * 64 + (id >> 3);
        const int nb = l >> 1, mb = l & 1;
        const int m0 = mb * 256, n0 = nb * 256;

        f32x4 acc[8][4] = {};

        auto stageHT = [&](int T){
            int kind = T & 3, ks = T >> 2;
            char* base = lds + (ks & 1) * BUF + kind * HT;
            const unsigned short* hi = (kind < 2) ? Ahi : Bhi;
            const unsigned short* lo = (kind < 2) ? Alo : Blo;
            int ld = (kind < 2) ? lda : ldb;
            int r0 = ((kind < 2) ? m0 : n0) + (kind & 1) * 128;
            int k0 = ks * KS;
            #pragma unroll
            for (int r = 0; r < 2; r++){
                int G = r * STG + tid, row = G >> 3, slot = G & 7, s0 = slot ^ (row & 7);
                const unsigned short* s = ((s0 < 4) ? hi : lo) + (size_t)(r0 + row) * ld + k0 + (s0 & 3) * 8;
                __builtin_amdgcn_global_load_lds(
                    (const __attribute__((address_space(1))) void*)s,
                    (__attribute__((address_space(3))) void*)(base + (r * STG + (tid & ~63)) * 16), 16, 0, 0);
            }
        };

        const int xh = (lg ^ (lr & 7)) << 4;
        const int xl = ((4 + lg) ^ (lr & 7)) << 4;

        stageHT(0); stageHT(1); stageHT(2); stageHT(3);
        if (nk > 1){
            stageHT(6); stageHT(7);
            asm volatile("s_waitcnt vmcnt(4)" ::: "memory");
        } else {
            asm volatile("s_waitcnt vmcnt(0)" ::: "memory");
        }
        __builtin_amdgcn_s_barrier();                       // arrival 1 (prologue)

        for (int kt = 0; kt < nk; kt++){
            const char* Ab = lds + (kt & 1) * BUF;
            const char* Bb = Ab + 2 * HT;
            bf16x8 bh[4], bl[4];
            #pragma unroll
            for (int q = 0; q < 4; q++){
                if (q < 2){ if (kt + 1 < nk) stageHT(4 * (kt + 1) + q); }
                else      { if (kt + 2 < nk) stageHT(4 * (kt + 2) + q); }
                if (q == 0){
                    #pragma unroll
                    for (int nf = 0; nf < 4; nf++){
                        const char* rp = Bb + (wn * 64 + nf * 16 + lr) * 128;
                        bh[nf] = *(const bf16x8*)(rp + xh);
                        bl[nf] = *(const bf16x8*)(rp + xl);
                    }
                }
                const char* rp0 = Ab + (wm * 128 + q * 32 + lr) * 128;
                const char* rp1 = rp0 + 16 * 128;
                bf16x8 a0h = *(const bf16x8*)(rp0 + xh);
                bf16x8 a0l = *(const bf16x8*)(rp0 + xl);
                bf16x8 a1h = *(const bf16x8*)(rp1 + xh);
                bf16x8 a1l = *(const bf16x8*)(rp1 + xl);
                asm volatile("s_barrier" ::: "memory");     // phase barrier A
                asm volatile("s_waitcnt lgkmcnt(0)" ::: "memory");
                __builtin_amdgcn_sched_barrier(0);
                __builtin_amdgcn_s_setprio(1);
                #pragma unroll
                for (int nf = 0; nf < 4; nf++)
                    acc[2*q  ][nf] = __builtin_amdgcn_mfma_f32_16x16x32_bf16(a0h, bh[nf], acc[2*q  ][nf], 0, 0, 0);
                #pragma unroll
                for (int nf = 0; nf < 4; nf++)
                    acc[2*q+1][nf] = __builtin_amdgcn_mfma_f32_16x16x32_bf16(a1h, bh[nf], acc[2*q+1][nf], 0, 0, 0);
                #pragma unroll
                for (int nf = 0; nf < 4; nf++)
                    acc[2*q  ][nf] = __builtin_amdgcn_mfma_f32_16x16x32_bf16(a0l, bl[nf], acc[2*q  ][nf], 0, 0, 0);
                #pragma unroll
                for (int nf = 0; nf < 4; nf++)
                    acc[2*q+1][nf] = __builtin_amdgcn_mfma_f32_16x16x32_bf16(a1l, bl[nf], acc[2*q+1][nf], 0, 0, 0);
                __builtin_amdgcn_s_setprio(0);
                if (q == 3){
                    if (kt < nk - 2)       asm volatile("s_waitcnt vmcnt(4)" ::: "memory");
                    else if (kt == nk - 2) asm volatile("s_waitcnt vmcnt(0)" ::: "memory");
                }
                asm volatile("s_barrier" ::: "memory");     // phase barrier B
            }
        }

        if constexpr (EPI == EPI_TOP2){
            T2* t2l = (T2*)lds;   // [4][256]
            #pragma unroll
            for (int mf = 0; mf < 8; mf++){
                #pragma unroll
                for (int r = 0; r < 4; r++){
                    T2 t = t2_init();
                    #pragma unroll
                    for (int nf = 0; nf < 4; nf++){
                        int gc = n0 + wn * 64 + nf * 16 + lr;
                        t2_add(t, acc[mf][nf][r], gc);
                    }
                    #pragma unroll
                    for (int m = 1; m < 16; m <<= 1){
                        float ov1 = __shfl_xor(t.v1, m), ov2 = __shfl_xor(t.v2, m);
                        int   oi1 = __shfl_xor(t.i1, m), oi2 = __shfl_xor(t.i2, m);
                        t2_add(t, ov1, oi1); t2_add(t, ov2, oi2);
                    }
                    if (lr == 0){
                        int rowit = wm * 128 + mf * 16 + lg * 4 + r;
                        t2l[wn * 256 + rowit] = t;
                    }
                }
            }
            asm volatile("s_waitcnt lgkmcnt(0)" ::: "memory");
            __builtin_amdgcn_s_barrier();                    // epilogue arrival (98)
            if (tid < 256){
                T2 t = t2l[tid];
                #pragma unroll
                for (int w = 1; w < 4; w++){
                    T2 o = t2l[w * 256 + tid];
                    t2_add(t, o.v1, o.i1); t2_add(t, o.v2, o.i2);
                }
                f32x4 pk; pk[0] = t.v1; pk[1] = __int_as_float(t.i1); pk[2] = t.v2; pk[3] = __int_as_float(t.i2);
                ((f32x4*)outp)[(size_t)nb * Mtot + (m0 + tid)] = pk;
            }
        } else if constexpr (EPI == EPI_SCALE){
            float sc = scale_ptr[0];
            #pragma unroll
            for (int mf = 0; mf < 8; mf++)
            #pragma unroll
            for (int nf = 0; nf < 4; nf++)
            #pragma unroll
            for (int r = 0; r < 4; r++){
                int grow = m0 + wm * 128 + mf * 16 + lg * 4 + r;
                int gcol = n0 + wn * 64 + nf * 16 + lr;
                outp[(size_t)grow * Nout + gcol] = acc[mf][nf][r] * sc;
            }
        }
    } else {
        // ---- convert waves (wid 8,9): mirrored barrier sequence ----
        const int cw = wid - 8;
        const size_t base = ((size_t)blockIdx.x * 2 + cw) * 64 + lane;
        const size_t stride = (size_t)512 * 2 * 64;     // 65536 chunks / sweep
        const size_t skip = (size_t)BATCH * DIM / 4;    // rows < BATCH owned by prep
        f32x4 v[2][4];
        auto issue = [&](int buf, int p){
            #pragma unroll
            for (int s = 0; s < 4; s++)
                v[buf][s] = __builtin_nontemporal_load((const f32x4*)cv_src + base + (size_t)(4*p + s) * stride);
        };
        auto flush = [&](int buf, int p){
            #pragma unroll
            for (int s = 0; s < 4; s++){
                size_t idx = base + (size_t)(4*p + s) * stride;
                if (cv_bf){
                    u16x4 h;
                    #pragma unroll
                    for (int j = 0; j < 4; j++) h[j] = f2bf(v[buf][s][j]);
                    *(u16x4*)(cv_bf + 4*idx) = h;
                }
                if (idx >= skip)
                    __builtin_nontemporal_store(v[buf][s], (f32x4*)cv_fp + idx);
            }
        };
        issue(0, 0);
        __builtin_amdgcn_s_barrier();                   // arrival 1 (prologue)
        const int nph = nk * 4;                         // 48 for K=768
        for (int p = 0; p < nph; p++){
            if (p + 1 < nph) issue((p + 1) & 1, p + 1);
            flush(p & 1, p);
            __builtin_amdgcn_s_barrier();               // matches phase barrier A
            __builtin_amdgcn_s_barrier();               // matches phase barrier B
        }
        if (EPI == EPI_TOP2) __builtin_amdgcn_s_barrier();  // matches epilogue
    }
}

// ---------- small GEMM (MLP layers): A bf16 hi/lo, B fp32 with in-kernel convert ----------
template<int BM,int BN,int WGM,int WGN,int EPI>
__global__ __launch_bounds__(WGM*WGN*64) void gemm_small(
    const unsigned short* __restrict__ Ahi, const unsigned short* __restrict__ Alo, int lda,
    const float* __restrict__ B, int ldb, int K,
    const float* __restrict__ bias,
    unsigned short* __restrict__ dsthi, unsigned short* __restrict__ dstlo, int ldd, int dstoff)
{
    constexpr int WM = BM / WGM, WN = BN / WGN;
    constexpr int MF = WM / 16, NF = WN / 16;
    constexpr int NT = WGM * WGN * 64;
    constexpr int ABYTES = BM * 128;
    constexpr int BBYTES = BN * 128;
    constexpr int BUF = ABYTES + BBYTES;
    static_assert(BN * 4 == NT, "");
    static_assert((BM * 8) % NT == 0, "");

    __shared__ __align__(16) char lds[2 * BUF];

    const int tid  = threadIdx.x;
    const int wid  = tid >> 6, lane = tid & 63;
    const int wm   = wid / WGN, wn = wid % WGN;
    const int lr   = lane & 15, lg = lane >> 4;
    const int nb   = blockIdx.x, mb = blockIdx.y;
    const int m0   = mb * BM, n0 = nb * BN;

    f32x4 acc[MF][NF] = {};
    f32x4 breg0, breg1;

    auto stageA = [&](int buf, int k0){
        char* base = lds + buf * BUF;
        constexpr int RA = BM * 8 / NT;
        #pragma unroll
        for (int r = 0; r < RA; r++){
            int G = r * NT + tid;
            int row = G >> 3, slot = G & 7;
            int s0 = slot ^ (row & 7);
            const unsigned short* src = ((s0 < 4) ? Ahi : Alo)
                + (size_t)(m0 + row) * lda + (k0 + (s0 & 3) * 8);
            char* ldst = base + r * NT * 16 + (tid & ~63) * 16;
            __builtin_amdgcn_global_load_lds(
                (const __attribute__((address_space(1))) void*)src,
                (__attribute__((address_space(3))) void*)ldst, 16, 0, 0);
        }
    };
    auto loadB = [&](int kt){
        int k0 = kt * 32;
        int row = tid >> 2, quad = tid & 3;
        const float* bp = B + (size_t)(n0 + row) * ldb + k0 + quad * 8;
        breg0 = *(const f32x4*)bp;
        breg1 = *(const f32x4*)(bp + 4);
    };
    auto writeB = [&](int buf){
        char* base = lds + buf * BUF + ABYTES;
        int row = tid >> 2, quad = tid & 3;
        u16x8 h8, l8;
        #pragma unroll
        for (int j = 0; j < 8; j++){
            float x = (j < 4) ? breg0[j] : breg1[j - 4];
            unsigned short h = f2bf(x);
            h8[j] = h; l8[j] = f2bf(x - bf2f(h));
        }
        int sh = quad ^ (row & 7), sl = (4 + quad) ^ (row & 7);
        *(u16x8*)(base + row * 128 + sh * 16) = h8;
        *(u16x8*)(base + row * 128 + sl * 16) = l8;
    };
    auto compute = [&](int buf){
        const char* Ab = lds + buf * BUF;
        const char* Bb = Ab + ABYTES;
        bf16x8 ah[MF], al[MF], bh[NF], bl[NF];
        #pragma unroll
        for (int mf = 0; mf < MF; mf++){
            int row = wm * WM + mf * 16 + lr;
            const char* rp = Ab + row * 128;
            ah[mf] = *(const bf16x8*)(rp + ((lg ^ (row & 7)) << 4));
            al[mf] = *(const bf16x8*)(rp + (((4 + lg) ^ (row & 7)) << 4));
        }
        #pragma unroll
        for (int nf = 0; nf < NF; nf++){
            int row = wn * WN + nf * 16 + lr;
            const char* rp = Bb + row * 128;
            bh[nf] = *(const bf16x8*)(rp + ((lg ^ (row & 7)) << 4));
            bl[nf] = *(const bf16x8*)(rp + (((4 + lg) ^ (row & 7)) << 4));
        }
        #pragma unroll
        for (int mf = 0; mf < MF; mf++)
        #pragma unroll
        for (int nf = 0; nf < NF; nf++){
            acc[mf][nf] = __builtin_amdgcn_mfma_f32_16x16x32_bf16(ah[mf], bh[nf], acc[mf][nf], 0, 0, 0);
            acc[mf][nf] = __builtin_amdgcn_mfma_f32_16x16x32_bf16(al[mf], bh[nf], acc[mf][nf], 0, 0, 0);
            acc[mf][nf] = __builtin_amdgcn_mfma_f32_16x16x32_bf16(ah[mf], bl[nf], acc[mf][nf], 0, 0, 0);
        }
    };

    stageA(0, 0); loadB(0); writeB(0);
    __syncthreads();
    const int nk = K / 32;
    int cur = 0;
    for (int kt = 0; kt < nk; kt++){
        if (kt + 1 < nk){ stageA(cur ^ 1, (kt + 1) * 32); loadB(kt + 1); }
        compute(cur);
        if (kt + 1 < nk){ writeB(cur ^ 1); }
        __syncthreads();
        cur ^= 1;
    }

    #pragma unroll
    for (int mf = 0; mf < MF; mf++)
    #pragma unroll
    for (int nf = 0; nf < NF; nf++)
    #pragma unroll
    for (int r = 0; r < 4; r++){
        int grow = m0 + wm * WM + mf * 16 + lg * 4 + r;
        int gcol = n0 + wn * WN + nf * 16 + lr;
        float c = acc[mf][nf][r] + bias[gcol];
        if (EPI == EPI_BIAS_RELU) c = fmaxf(c, 0.f);
        unsigned short h = f2bf(c);
        size_t o = (size_t)grow * ldd + dstoff + gcol;
        dsthi[o] = h;
        dstlo[o] = f2bf(c - bf2f(h));
    }
}

// ---------- phase B: global top-4 + exact fp32 rescore + fused gather ----------
__global__ __launch_bounds__(256) void phaseB_kernel(
    const f32x4* __restrict__ top2ws, int ntiles,
    const float* __restrict__ img_f, const float* __restrict__ qtxt,
    float* __restrict__ out_ind,
    unsigned short* __restrict__ X1hi, unsigned short* __restrict__ X1lo)
{
    __shared__ float vals[512];
    __shared__ int   inds[512];
    __shared__ float red[4];
    __shared__ int   redi[4];
    __shared__ int   cands[4];
    __shared__ float cscore[4];
    __shared__ int   finali;
    const int row = blockIdx.x, tid = threadIdx.x;

    if (tid < ntiles){
        f32x4 e = top2ws[(size_t)tid * BATCH + row];
        vals[2*tid]   = e[0]; inds[2*tid]   = __float_as_int(e[1]);
        vals[2*tid+1] = e[2]; inds[2*tid+1] = __float_as_int(e[3]);
    }
    __syncthreads();

    for (int it = 0; it < 4; it++){
        float v = vals[tid]; int i = inds[tid];
        {
            float v2 = vals[tid+256]; int i2 = inds[tid+256];
            if (v2 > v || (v2 == v && i2 < i)){ v = v2; i = i2; }
        }
        #pragma unroll
        for (int m = 1; m < 64; m <<= 1){
            float ov = __shfl_xor(v, m); int oi = __shfl_xor(i, m);
            if (ov > v || (ov == v && oi < i)){ v = ov; i = oi; }
        }
        if ((tid & 63) == 0){ red[tid>>6] = v; redi[tid>>6] = i; }
        __syncthreads();
        if (tid == 0){
            float bv = red[0]; int bi = redi[0];
            #pragma unroll
            for (int w = 1; w < 4; w++)
                if (red[w] > bv || (red[w] == bv && redi[w] < bi)){ bv = red[w]; bi = redi[w]; }
            cands[it] = bi;
        }
        __syncthreads();
        if (inds[tid]     == cands[it]) vals[tid]     = -3.4e38f;
        if (inds[tid+256] == cands[it]) vals[tid+256] = -3.4e38f;
        __syncthreads();
    }

    const float* a = img_f + (size_t)row * DIM;
    float a0 = a[tid], a1 = a[tid + 256], a2 = a[tid + 512];
    for (int c = 0; c < 4; c++){
        const float* bp = qtxt + (size_t)cands[c] * DIM;
        float s = a0 * bp[tid] + a1 * bp[tid + 256] + a2 * bp[tid + 512];
        #pragma unroll
        for (int m = 1; m < 64; m <<= 1) s += __shfl_xor(s, m);
        if ((tid & 63) == 0) red[tid>>6] = s;
        __syncthreads();
        if (tid == 0) cscore[c] = red[0] + red[1] + red[2] + red[3];
        __syncthreads();
    }
    if (tid == 0){
        float bs = cscore[0]; int bi = cands[0];
        #pragma unroll
        for (int c = 1; c < 4; c++)
            if (cscore[c] > bs || (cscore[c] == bs && cands[c] < bi)){ bs = cscore[c]; bi = cands[c]; }
        out_ind[row] = (float)bi;
        finali = bi;
    }
    __syncthreads();

    const float* src = qtxt + (size_t)finali * DIM;
    for (int c = tid; c < DIM; c += 256){
        float x = src[c];
        unsigned short h = f2bf(x);
        X1hi[(size_t)row * DIM2 + DIM + c] = h;
        X1lo[(size_t)row * DIM2 + DIM + c] = f2bf(x - bf2f(h));
    }
}

extern "C" void kernel_launch(void* const* d_in, const int* in_sizes, int n_in,
                              void* d_out, int out_size, void* d_ws, size_t ws_size,
                              hipStream_t stream)
{
    (void)in_sizes; (void)n_in; (void)out_size; (void)ws_size;
    const float* img  = (const float*)d_in[0];
    const float* txt  = (const float*)d_in[1];
    const float* qimg = (const float*)d_in[2];
    const float* qtxt = (const float*)d_in[3];
    const float* Wd   = (const float*)d_in[4];
    const float* bd   = (const float*)d_in[5];
    const float* Wc   = (const float*)d_in[6];
    const float* bc   = (const float*)d_in[7];
    const float* ls   = (const float*)d_in[8];

    float* out0 = (float*)d_out;                    // logits [512][65536]
    float* out1 = out0 + (size_t)BATCH * NQ;        // ind_similar [512] (as f32)
    float* out2 = out1 + BATCH;                     // new_queue_img [65536][768]
    float* out3 = out2 + (size_t)NQ * DIM;          // new_queue_txt [65536][768]

    char* w = (char*)d_ws;
    auto alloc = [&](size_t bytes){ char* p = w; w += (bytes + 255) & ~(size_t)255; return p; };
    unsigned short* X1hi  = (unsigned short*)alloc((size_t)BATCH * DIM2 * 2);
    unsigned short* X1lo  = (unsigned short*)alloc((size_t)BATCH * DIM2 * 2);
    unsigned short* X2hi  = (unsigned short*)alloc((size_t)BATCH * DIM2 * 2);
    unsigned short* X2lo  = (unsigned short*)alloc((size_t)BATCH * DIM2 * 2);
    unsigned short* combhi= (unsigned short*)alloc((size_t)BATCH * DIM * 2);
    unsigned short* comblo= (unsigned short*)alloc((size_t)BATCH * DIM * 2);
    float* img_f  = (float*)alloc((size_t)BATCH * DIM * 4);
    float* txt_f  = (float*)alloc((size_t)BATCH * DIM * 4);
    float* Td     = (float*)alloc((size_t)DIM * DIM2 * 4);
    float* Tc     = (float*)alloc((size_t)DIM * DIM2 * 4);
    float* top2ws = (float*)alloc((size_t)(NQ / 256) * BATCH * 16);
    unsigned short* Bt_hi = (unsigned short*)alloc((size_t)NQ * DIM * 2);
    unsigned short* Bi_hi = (unsigned short*)alloc((size_t)NQ * DIM * 2);

    // 1) prep: qtxt -> bf16 + feature prep + weight transpose
    prep_all<<<dim3(CONVB + 2 * BATCH + 2304), dim3(256), 0, stream>>>(
        img, txt, qtxt, Wd, Wc, Bt_hi,
        img_f, txt_f, X2hi, X2lo, X1hi, X1lo, out2, out3, Td, Tc);

    // 2) retrieval GEMM + top2; convert waves: qimg -> Bi_hi + out2 passthrough
    gemm_big<EPI_TOP2><<<dim3(512), dim3(640), 0, stream>>>(
        X2hi, X2hi + 32, DIM2, Bt_hi, Bt_hi + 32, DIM, DIM, NQ, top2ws, nullptr, BATCH,
        qimg, Bi_hi, out2);

    // 3) global top-4 + exact rescore -> ind_similar + fused gather
    phaseB_kernel<<<dim3(BATCH), dim3(256), 0, stream>>>(
        (const f32x4*)top2ws, NQ / 256, img_f, qtxt, out1, X1hi, X1lo);

    // 4) diff = relu(X1 @ W_diff + b_diff) -> X2[:, 768:] (split)
    gemm_small<64,64,2,2,EPI_BIAS_RELU><<<dim3(DIM / 64, BATCH / 64), dim3(256), 0, stream>>>(
        X1hi, X1lo, DIM2, Td, DIM2, DIM2, bd, X2hi, X2lo, DIM2, DIM);

    // 5) combined = X2 @ W_comb + b_comb -> comb hi/lo
    gemm_small<64,64,2,2,EPI_BIAS><<<dim3(DIM / 64, BATCH / 64), dim3(256), 0, stream>>>(
        X2hi, X2lo, DIM2, Tc, DIM2, DIM2, bc, combhi, comblo, DIM, 0);

    // 6) logits GEMM; convert waves: qtxt -> out3 passthrough
    gemm_big<EPI_SCALE><<<dim3(512), dim3(640), 0, stream>>>(
        combhi, combhi + 32, DIM, Bi_hi, Bi_hi + 32, DIM, DIM, NQ, out0, ls, BATCH,
        qtxt, (unsigned short*)nullptr, out3);
}

// Round 12
// 938.560 us; speedup vs baseline: 1.2568x; 1.2568x over previous
//
#include <hip/hip_runtime.h>
#include <stdint.h>
#include <stddef.h>

#define BATCH 512
#define NQ    65536
#define DIM   768
#define DIM2  1536
#define CONVB 2048

typedef __attribute__((ext_vector_type(4))) float f32x4;
typedef __attribute__((ext_vector_type(4))) unsigned short u16x4;
typedef __attribute__((ext_vector_type(8))) unsigned short u16x8;
typedef __attribute__((ext_vector_type(8))) __bf16 bf16x8;

// ---------- fp32 <-> bf16 (round-to-nearest-even) ----------
static __device__ __forceinline__ unsigned short f2bf(float x){
    unsigned int u = __float_as_uint(x);
    unsigned int r = ((u >> 16) & 1u) + 0x7fffu;
    return (unsigned short)((u + r) >> 16);
}
static __device__ __forceinline__ float bf2f(unsigned short h){
    return __uint_as_float(((unsigned int)h) << 16);
}

// ---------- top-2 tracking ----------
struct T2 { float v1, v2; int i1, i2; };
static __device__ __forceinline__ void t2_add(T2& t, float v, int i){
    if (v > t.v1 || (v == t.v1 && i < t.i1)) { t.v2 = t.v1; t.i2 = t.i1; t.v1 = v; t.i1 = i; }
    else if (v > t.v2 || (v == t.v2 && i < t.i2)) { t.v2 = v; t.i2 = i; }
}
static __device__ __forceinline__ T2 t2_init(){ T2 t; t.v1 = -3.4e38f; t.v2 = -3.4e38f; t.i1 = 0x7fffffff; t.i2 = 0x7fffffff; return t; }

// ---------- prep_all: qtxt->bf16 + feature prep + weight transpose ----------
__global__ __launch_bounds__(256) void prep_all(
    const float* __restrict__ img, const float* __restrict__ txt,
    const float* __restrict__ qtxt,
    const float* __restrict__ Wd, const float* __restrict__ Wc,
    unsigned short* __restrict__ bthi,
    float* __restrict__ img_f, float* __restrict__ txt_f,
    unsigned short* __restrict__ X2hi, unsigned short* __restrict__ X2lo,
    unsigned short* __restrict__ X1hi, unsigned short* __restrict__ X1lo,
    float* __restrict__ out2, float* __restrict__ out3,
    float* __restrict__ Td, float* __restrict__ Tc)
{
    __shared__ float tbuf[32][33];
    __shared__ float red[4];
    const int b = blockIdx.x;
    if (b < CONVB){
        const size_t n4 = (size_t)NQ * DIM / 4;
        for (size_t i = (size_t)b * 256 + threadIdx.x; i < n4; i += (size_t)CONVB * 256){
            f32x4 v = ((const f32x4*)qtxt)[i];
            u16x4 h;
            #pragma unroll
            for (int j = 0; j < 4; j++) h[j] = f2bf(v[j]);
            *(u16x4*)(bthi + 4*i) = h;
        }
    } else if (b < CONVB + 2 * BATCH){
        const int b2 = b - CONVB;
        const bool isimg = (b2 < BATCH);
        const int row = isimg ? b2 : b2 - BATCH;
        const float* src = (isimg ? img : txt) + (size_t)row * DIM;
        float v[3];
        float ss = 0.f;
        #pragma unroll
        for (int i = 0; i < 3; i++){ v[i] = src[threadIdx.x + i*256]; ss += v[i]*v[i]; }
        #pragma unroll
        for (int m = 1; m < 64; m <<= 1) ss += __shfl_xor(ss, m);
        if ((threadIdx.x & 63) == 0) red[threadIdx.x >> 6] = ss;
        __syncthreads();
        float tot = red[0] + red[1] + red[2] + red[3];
        float scale = 1.0f / fmaxf(sqrtf(tot), 1e-12f);
        float* fdst = (isimg ? img_f : txt_f) + (size_t)row * DIM;
        float* odst = (isimg ? out2  : out3 ) + (size_t)row * DIM;
        unsigned short* hid = (isimg ? X2hi : X1hi) + (size_t)row * DIM2;
        unsigned short* lod = (isimg ? X2lo : X1lo) + (size_t)row * DIM2;
        #pragma unroll
        for (int i = 0; i < 3; i++){
            int c = threadIdx.x + i*256;
            float y = v[i] * scale;
            fdst[c] = y; odst[c] = y;
            unsigned short h = f2bf(y);
            hid[c] = h; lod[c] = f2bf(y - bf2f(h));
        }
    } else {
        int t = b - CONVB - 2 * BATCH;           // 0..2303
        const int z = t / 1152; t -= z * 1152;    // 1152 = 24 * 48
        const int x = t % 24, y = t / 24;
        const float* W = z ? Wc : Wd;
        float*       T = z ? Tc : Td;
        const int x0 = x * 32, y0 = y * 32;
        const int tx = threadIdx.x & 31, ty = threadIdx.x >> 5;
        #pragma unroll
        for (int i = 0; i < 32; i += 8)
            tbuf[ty + i][tx] = W[(size_t)(y0 + ty + i) * DIM + x0 + tx];
        __syncthreads();
        #pragma unroll
        for (int i = 0; i < 32; i += 8)
            T[(size_t)(x0 + ty + i) * DIM2 + y0 + tx] = tbuf[tx][ty + i];
    }
}

#define EPI_TOP2      0
#define EPI_BIAS_RELU 1
#define EPI_BIAS      2
#define EPI_SCALE     3

// ---------- big GEMM: 8-phase schedule + producer convert waves (rule-#20 fixed) ----
// Waves 0..7: R10's verified GEMM K-loop, byte-identical.
// Waves 8..9: convert role with NAMED double-buffer registers (a0..a3 / b0..b3) --
// all indices compile-time, no runtime-indexed arrays (R11's scratch-spill bug).
// Barrier ledger: GEMM arrivals = 1 + nk*4*2 (nk=12 -> 96) + (TOP2?1:0) = 97/98;
// convert arrivals = 1 + 24 iters * 4 + (TOP2?1:0) = 97/98. Matches.
template<int EPI>
__global__ __launch_bounds__(640, 1) void gemm_big(
    const unsigned short* __restrict__ Ahi, const unsigned short* __restrict__ Alo, int lda,
    const unsigned short* __restrict__ Bhi, const unsigned short* __restrict__ Blo, int ldb,
    int K, int Nout,
    float* __restrict__ outp, const float* __restrict__ scale_ptr, int Mtot,
    const float* __restrict__ cv_src, unsigned short* __restrict__ cv_bf,
    float* __restrict__ cv_fp)
{
    constexpr int STG = 512;            // GEMM staging thread count
    constexpr int KS = 64;
    constexpr int HT = 16384;           // half-tile bytes: 128 rows x 128B
    constexpr int BUF = 4 * HT;         // 64 KiB per K-step
    __shared__ __align__(16) char lds[2 * BUF];   // 128 KiB

    const int tid = threadIdx.x, lane = tid & 63, wid = tid >> 6;
    const int nk = K / KS;   // 12

    if (wid < 8){
        const int wm = wid >> 2, wn = wid & 3;
        const int lr = lane & 15, lg = lane >> 4;
        const int id = blockIdx.x;
        const int l  = (id & 7) * 64 + (id >> 3);
        const int nb = l >> 1, mb = l & 1;
        const int m0 = mb * 256, n0 = nb * 256;

        f32x4 acc[8][4] = {};

        auto stageHT = [&](int T){
            int kind = T & 3, ks = T >> 2;
            char* base = lds + (ks & 1) * BUF + kind * HT;
            const unsigned short* hi = (kind < 2) ? Ahi : Bhi;
            const unsigned short* lo = (kind < 2) ? Alo : Blo;
            int ld = (kind < 2) ? lda : ldb;
            int r0 = ((kind < 2) ? m0 : n0) + (kind & 1) * 128;
            int k0 = ks * KS;
            #pragma unroll
            for (int r = 0; r < 2; r++){
                int G = r * STG + tid, row = G >> 3, slot = G & 7, s0 = slot ^ (row & 7);
                const unsigned short* s = ((s0 < 4) ? hi : lo) + (size_t)(r0 + row) * ld + k0 + (s0 & 3) * 8;
                __builtin_amdgcn_global_load_lds(
                    (const __attribute__((address_space(1))) void*)s,
                    (__attribute__((address_space(3))) void*)(base + (r * STG + (tid & ~63)) * 16), 16, 0, 0);
            }
        };

        const int xh = (lg ^ (lr & 7)) << 4;
        const int xl = ((4 + lg) ^ (lr & 7)) << 4;

        stageHT(0); stageHT(1); stageHT(2); stageHT(3);
        if (nk > 1){
            stageHT(6); stageHT(7);
            asm volatile("s_waitcnt vmcnt(4)" ::: "memory");
        } else {
            asm volatile("s_waitcnt vmcnt(0)" ::: "memory");
        }
        __builtin_amdgcn_s_barrier();                       // arrival 1 (prologue)

        for (int kt = 0; kt < nk; kt++){
            const char* Ab = lds + (kt & 1) * BUF;
            const char* Bb = Ab + 2 * HT;
            bf16x8 bh[4], bl[4];
            #pragma unroll
            for (int q = 0; q < 4; q++){
                if (q < 2){ if (kt + 1 < nk) stageHT(4 * (kt + 1) + q); }
                else      { if (kt + 2 < nk) stageHT(4 * (kt + 2) + q); }
                if (q == 0){
                    #pragma unroll
                    for (int nf = 0; nf < 4; nf++){
                        const char* rp = Bb + (wn * 64 + nf * 16 + lr) * 128;
                        bh[nf] = *(const bf16x8*)(rp + xh);
                        bl[nf] = *(const bf16x8*)(rp + xl);
                    }
                }
                const char* rp0 = Ab + (wm * 128 + q * 32 + lr) * 128;
                const char* rp1 = rp0 + 16 * 128;
                bf16x8 a0h = *(const bf16x8*)(rp0 + xh);
                bf16x8 a0l = *(const bf16x8*)(rp0 + xl);
                bf16x8 a1h = *(const bf16x8*)(rp1 + xh);
                bf16x8 a1l = *(const bf16x8*)(rp1 + xl);
                asm volatile("s_barrier" ::: "memory");     // phase barrier A
                asm volatile("s_waitcnt lgkmcnt(0)" ::: "memory");
                __builtin_amdgcn_sched_barrier(0);
                __builtin_amdgcn_s_setprio(1);
                #pragma unroll
                for (int nf = 0; nf < 4; nf++)
                    acc[2*q  ][nf] = __builtin_amdgcn_mfma_f32_16x16x32_bf16(a0h, bh[nf], acc[2*q  ][nf], 0, 0, 0);
                #pragma unroll
                for (int nf = 0; nf < 4; nf++)
                    acc[2*q+1][nf] = __builtin_amdgcn_mfma_f32_16x16x32_bf16(a1h, bh[nf], acc[2*q+1][nf], 0, 0, 0);
                #pragma unroll
                for (int nf = 0; nf < 4; nf++)
                    acc[2*q  ][nf] = __builtin_amdgcn_mfma_f32_16x16x32_bf16(a0l, bl[nf], acc[2*q  ][nf], 0, 0, 0);
                #pragma unroll
                for (int nf = 0; nf < 4; nf++)
                    acc[2*q+1][nf] = __builtin_amdgcn_mfma_f32_16x16x32_bf16(a1l, bl[nf], acc[2*q+1][nf], 0, 0, 0);
                __builtin_amdgcn_s_setprio(0);
                if (q == 3){
                    if (kt < nk - 2)       asm volatile("s_waitcnt vmcnt(4)" ::: "memory");
                    else if (kt == nk - 2) asm volatile("s_waitcnt vmcnt(0)" ::: "memory");
                }
                asm volatile("s_barrier" ::: "memory");     // phase barrier B
            }
        }

        if constexpr (EPI == EPI_TOP2){
            T2* t2l = (T2*)lds;   // [4][256]
            #pragma unroll
            for (int mf = 0; mf < 8; mf++){
                #pragma unroll
                for (int r = 0; r < 4; r++){
                    T2 t = t2_init();
                    #pragma unroll
                    for (int nf = 0; nf < 4; nf++){
                        int gc = n0 + wn * 64 + nf * 16 + lr;
                        t2_add(t, acc[mf][nf][r], gc);
                    }
                    #pragma unroll
                    for (int m = 1; m < 16; m <<= 1){
                        float ov1 = __shfl_xor(t.v1, m), ov2 = __shfl_xor(t.v2, m);
                        int   oi1 = __shfl_xor(t.i1, m), oi2 = __shfl_xor(t.i2, m);
                        t2_add(t, ov1, oi1); t2_add(t, ov2, oi2);
                    }
                    if (lr == 0){
                        int rowit = wm * 128 + mf * 16 + lg * 4 + r;
                        t2l[wn * 256 + rowit] = t;
                    }
                }
            }
            asm volatile("s_waitcnt lgkmcnt(0)" ::: "memory");
            __builtin_amdgcn_s_barrier();                    // epilogue arrival (98)
            if (tid < 256){
                T2 t = t2l[tid];
                #pragma unroll
                for (int w = 1; w < 4; w++){
                    T2 o = t2l[w * 256 + tid];
                    t2_add(t, o.v1, o.i1); t2_add(t, o.v2, o.i2);
                }
                f32x4 pk; pk[0] = t.v1; pk[1] = __int_as_float(t.i1); pk[2] = t.v2; pk[3] = __int_as_float(t.i2);
                ((f32x4*)outp)[(size_t)nb * Mtot + (m0 + tid)] = pk;
            }
        } else if constexpr (EPI == EPI_SCALE){
            float sc = scale_ptr[0];
            #pragma unroll
            for (int mf = 0; mf < 8; mf++)
            #pragma unroll
            for (int nf = 0; nf < 4; nf++)
            #pragma unroll
            for (int r = 0; r < 4; r++){
                int grow = m0 + wm * 128 + mf * 16 + lg * 4 + r;
                int gcol = n0 + wn * 64 + nf * 16 + lr;
                outp[(size_t)grow * Nout + gcol] = acc[mf][nf][r] * sc;
            }
        }
    } else {
        // ---- convert waves (wid 8,9): named-register double buffer, static indices ----
        const int cw = wid - 8;
        const size_t base = ((size_t)blockIdx.x * 2 + cw) * 64 + lane;
        const size_t stride = (size_t)512 * 2 * 64;     // 65536 chunks / sweep
        const size_t skip = (size_t)BATCH * DIM / 4;    // rows < BATCH owned by prep
        const bool has_bf = (cv_bf != nullptr);

        f32x4 a0, a1, a2, a3, b0, b1, b2, b3;

        auto flush1 = [&](f32x4 v, size_t idx){
            if (has_bf){
                u16x4 h;
                #pragma unroll
                for (int j = 0; j < 4; j++) h[j] = f2bf(v[j]);
                *(u16x4*)(cv_bf + 4*idx) = h;
            }
            if (idx >= skip)
                __builtin_nontemporal_store(v, (f32x4*)cv_fp + idx);
        };

#define CV_ISSUE(r0,r1,r2,r3,p) do{ size_t o_ = base + (size_t)(4*(p)) * stride;            \
        r0 = __builtin_nontemporal_load((const f32x4*)cv_src + o_);                          \
        r1 = __builtin_nontemporal_load((const f32x4*)cv_src + o_ + stride);                 \
        r2 = __builtin_nontemporal_load((const f32x4*)cv_src + o_ + 2*stride);               \
        r3 = __builtin_nontemporal_load((const f32x4*)cv_src + o_ + 3*stride); }while(0)
#define CV_FLUSH(r0,r1,r2,r3,p) do{ size_t o_ = base + (size_t)(4*(p)) * stride;            \
        flush1(r0, o_); flush1(r1, o_ + stride);                                             \
        flush1(r2, o_ + 2*stride); flush1(r3, o_ + 3*stride); }while(0)

        CV_ISSUE(a0,a1,a2,a3, 0);
        __builtin_amdgcn_s_barrier();                   // arrival 1 (prologue)
        const int nph = nk * 4;                         // 48 (even)
        for (int p = 0; p < nph; p += 2){
            CV_ISSUE(b0,b1,b2,b3, p + 1);
            CV_FLUSH(a0,a1,a2,a3, p);
            __builtin_amdgcn_s_barrier();               // matches phase barrier A
            __builtin_amdgcn_s_barrier();               // matches phase barrier B
            if (p + 2 < nph) CV_ISSUE(a0,a1,a2,a3, p + 2);
            CV_FLUSH(b0,b1,b2,b3, p + 1);
            __builtin_amdgcn_s_barrier();               // matches phase barrier A
            __builtin_amdgcn_s_barrier();               // matches phase barrier B
        }
        if (EPI == EPI_TOP2) __builtin_amdgcn_s_barrier();  // matches epilogue
#undef CV_ISSUE
#undef CV_FLUSH
    }
}

// ---------- small GEMM (MLP layers): A bf16 hi/lo, B fp32 with in-kernel convert ----------
template<int BM,int BN,int WGM,int WGN,int EPI>
__global__ __launch_bounds__(WGM*WGN*64) void gemm_small(
    const unsigned short* __restrict__ Ahi, const unsigned short* __restrict__ Alo, int lda,
    const float* __restrict__ B, int ldb, int K,
    const float* __restrict__ bias,
    unsigned short* __restrict__ dsthi, unsigned short* __restrict__ dstlo, int ldd, int dstoff)
{
    constexpr int WM = BM / WGM, WN = BN / WGN;
    constexpr int MF = WM / 16, NF = WN / 16;
    constexpr int NT = WGM * WGN * 64;
    constexpr int ABYTES = BM * 128;
    constexpr int BBYTES = BN * 128;
    constexpr int BUF = ABYTES + BBYTES;
    static_assert(BN * 4 == NT, "");
    static_assert((BM * 8) % NT == 0, "");

    __shared__ __align__(16) char lds[2 * BUF];

    const int tid  = threadIdx.x;
    const int wid  = tid >> 6, lane = tid & 63;
    const int wm   = wid / WGN, wn = wid % WGN;
    const int lr   = lane & 15, lg = lane >> 4;
    const int nb   = blockIdx.x, mb = blockIdx.y;
    const int m0   = mb * BM, n0 = nb * BN;

    f32x4 acc[MF][NF] = {};
    f32x4 breg0, breg1;

    auto stageA = [&](int buf, int k0){
        char* base = lds + buf * BUF;
        constexpr int RA = BM * 8 / NT;
        #pragma unroll
        for (int r = 0; r < RA; r++){
            int G = r * NT + tid;
            int row = G >> 3, slot = G & 7;
            int s0 = slot ^ (row & 7);
            const unsigned short* src = ((s0 < 4) ? Ahi : Alo)
                + (size_t)(m0 + row) * lda + (k0 + (s0 & 3) * 8);
            char* ldst = base + r * NT * 16 + (tid & ~63) * 16;
            __builtin_amdgcn_global_load_lds(
                (const __attribute__((address_space(1))) void*)src,
                (__attribute__((address_space(3))) void*)ldst, 16, 0, 0);
        }
    };
    auto loadB = [&](int kt){
        int k0 = kt * 32;
        int row = tid >> 2, quad = tid & 3;
        const float* bp = B + (size_t)(n0 + row) * ldb + k0 + quad * 8;
        breg0 = *(const f32x4*)bp;
        breg1 = *(const f32x4*)(bp + 4);
    };
    auto writeB = [&](int buf){
        char* base = lds + buf * BUF + ABYTES;
        int row = tid >> 2, quad = tid & 3;
        u16x8 h8, l8;
        #pragma unroll
        for (int j = 0; j < 8; j++){
            float x = (j < 4) ? breg0[j] : breg1[j - 4];
            unsigned short h = f2bf(x);
            h8[j] = h; l8[j] = f2bf(x - bf2f(h));
        }
        int sh = quad ^ (row & 7), sl = (4 + quad) ^ (row & 7);
        *(u16x8*)(base + row * 128 + sh * 16) = h8;
        *(u16x8*)(base + row * 128 + sl * 16) = l8;
    };
    auto compute = [&](int buf){
        const char* Ab = lds + buf * BUF;
        const char* Bb = Ab + ABYTES;
        bf16x8 ah[MF], al[MF], bh[NF], bl[NF];
        #pragma unroll
        for (int mf = 0; mf < MF; mf++){
            int row = wm * WM + mf * 16 + lr;
            const char* rp = Ab + row * 128;
            ah[mf] = *(const bf16x8*)(rp + ((lg ^ (row & 7)) << 4));
            al[mf] = *(const bf16x8*)(rp + (((4 + lg) ^ (row & 7)) << 4));
        }
        #pragma unroll
        for (int nf = 0; nf < NF; nf++){
            int row = wn * WN + nf * 16 + lr;
            const char* rp = Bb + row * 128;
            bh[nf] = *(const bf16x8*)(rp + ((lg ^ (row & 7)) << 4));
            bl[nf] = *(const bf16x8*)(rp + (((4 + lg) ^ (row & 7)) << 4));
        }
        #pragma unroll
        for (int mf = 0; mf < MF; mf++)
        #pragma unroll
        for (int nf = 0; nf < NF; nf++){
            acc[mf][nf] = __builtin_amdgcn_mfma_f32_16x16x32_bf16(ah[mf], bh[nf], acc[mf][nf], 0, 0, 0);
            acc[mf][nf] = __builtin_amdgcn_mfma_f32_16x16x32_bf16(al[mf], bh[nf], acc[mf][nf], 0, 0, 0);
            acc[mf][nf] = __builtin_amdgcn_mfma_f32_16x16x32_bf16(ah[mf], bl[nf], acc[mf][nf], 0, 0, 0);
        }
    };

    stageA(0, 0); loadB(0); writeB(0);
    __syncthreads();
    const int nk = K / 32;
    int cur = 0;
    for (int kt = 0; kt < nk; kt++){
        if (kt + 1 < nk){ stageA(cur ^ 1, (kt + 1) * 32); loadB(kt + 1); }
        compute(cur);
        if (kt + 1 < nk){ writeB(cur ^ 1); }
        __syncthreads();
        cur ^= 1;
    }

    #pragma unroll
    for (int mf = 0; mf < MF; mf++)
    #pragma unroll
    for (int nf = 0; nf < NF; nf++)
    #pragma unroll
    for (int r = 0; r < 4; r++){
        int grow = m0 + wm * WM + mf * 16 + lg * 4 + r;
        int gcol = n0 + wn * WN + nf * 16 + lr;
        float c = acc[mf][nf][r] + bias[gcol];
        if (EPI == EPI_BIAS_RELU) c = fmaxf(c, 0.f);
        unsigned short h = f2bf(c);
        size_t o = (size_t)grow * ldd + dstoff + gcol;
        dsthi[o] = h;
        dstlo[o] = f2bf(c - bf2f(h));
    }
}

// ---------- phase B: global top-4 + exact fp32 rescore + fused gather ----------
__global__ __launch_bounds__(256) void phaseB_kernel(
    const f32x4* __restrict__ top2ws, int ntiles,
    const float* __restrict__ img_f, const float* __restrict__ qtxt,
    float* __restrict__ out_ind,
    unsigned short* __restrict__ X1hi, unsigned short* __restrict__ X1lo)
{
    __shared__ float vals[512];
    __shared__ int   inds[512];
    __shared__ float red[4];
    __shared__ int   redi[4];
    __shared__ int   cands[4];
    __shared__ float cscore[4];
    __shared__ int   finali;
    const int row = blockIdx.x, tid = threadIdx.x;

    if (tid < ntiles){
        f32x4 e = top2ws[(size_t)tid * BATCH + row];
        vals[2*tid]   = e[0]; inds[2*tid]   = __float_as_int(e[1]);
        vals[2*tid+1] = e[2]; inds[2*tid+1] = __float_as_int(e[3]);
    }
    __syncthreads();

    for (int it = 0; it < 4; it++){
        float v = vals[tid]; int i = inds[tid];
        {
            float v2 = vals[tid+256]; int i2 = inds[tid+256];
            if (v2 > v || (v2 == v && i2 < i)){ v = v2; i = i2; }
        }
        #pragma unroll
        for (int m = 1; m < 64; m <<= 1){
            float ov = __shfl_xor(v, m); int oi = __shfl_xor(i, m);
            if (ov > v || (ov == v && oi < i)){ v = ov; i = oi; }
        }
        if ((tid & 63) == 0){ red[tid>>6] = v; redi[tid>>6] = i; }
        __syncthreads();
        if (tid == 0){
            float bv = red[0]; int bi = redi[0];
            #pragma unroll
            for (int w = 1; w < 4; w++)
                if (red[w] > bv || (red[w] == bv && redi[w] < bi)){ bv = red[w]; bi = redi[w]; }
            cands[it] = bi;
        }
        __syncthreads();
        if (inds[tid]     == cands[it]) vals[tid]     = -3.4e38f;
        if (inds[tid+256] == cands[it]) vals[tid+256] = -3.4e38f;
        __syncthreads();
    }

    const float* a = img_f + (size_t)row * DIM;
    float a0 = a[tid], a1 = a[tid + 256], a2 = a[tid + 512];
    for (int c = 0; c < 4; c++){
        const float* bp = qtxt + (size_t)cands[c] * DIM;
        float s = a0 * bp[tid] + a1 * bp[tid + 256] + a2 * bp[tid + 512];
        #pragma unroll
        for (int m = 1; m < 64; m <<= 1) s += __shfl_xor(s, m);
        if ((tid & 63) == 0) red[tid>>6] = s;
        __syncthreads();
        if (tid == 0) cscore[c] = red[0] + red[1] + red[2] + red[3];
        __syncthreads();
    }
    if (tid == 0){
        float bs = cscore[0]; int bi = cands[0];
        #pragma unroll
        for (int c = 1; c < 4; c++)
            if (cscore[c] > bs || (cscore[c] == bs && cands[c] < bi)){ bs = cscore[c]; bi = cands[c]; }
        out_ind[row] = (float)bi;
        finali = bi;
    }
    __syncthreads();

    const float* src = qtxt + (size_t)finali * DIM;
    for (int c = tid; c < DIM; c += 256){
        float x = src[c];
        unsigned short h = f2bf(x);
        X1hi[(size_t)row * DIM2 + DIM + c] = h;
        X1lo[(size_t)row * DIM2 + DIM + c] = f2bf(x - bf2f(h));
    }
}

extern "C" void kernel_launch(void* const* d_in, const int* in_sizes, int n_in,
                              void* d_out, int out_size, void* d_ws, size_t ws_size,
                              hipStream_t stream)
{
    (void)in_sizes; (void)n_in; (void)out_size; (void)ws_size;
    const float* img  = (const float*)d_in[0];
    const float* txt  = (const float*)d_in[1];
    const float* qimg = (const float*)d_in[2];
    const float* qtxt = (const float*)d_in[3];
    const float* Wd   = (const float*)d_in[4];
    const float* bd   = (const float*)d_in[5];
    const float* Wc   = (const float*)d_in[6];
    const float* bc   = (const float*)d_in[7];
    const float* ls   = (const float*)d_in[8];

    float* out0 = (float*)d_out;                    // logits [512][65536]
    float* out1 = out0 + (size_t)BATCH * NQ;        // ind_similar [512] (as f32)
    float* out2 = out1 + BATCH;                     // new_queue_img [65536][768]
    float* out3 = out2 + (size_t)NQ * DIM;          // new_queue_txt [65536][768]

    char* w = (char*)d_ws;
    auto alloc = [&](size_t bytes){ char* p = w; w += (bytes + 255) & ~(size_t)255; return p; };
    unsigned short* X1hi  = (unsigned short*)alloc((size_t)BATCH * DIM2 * 2);
    unsigned short* X1lo  = (unsigned short*)alloc((size_t)BATCH * DIM2 * 2);
    unsigned short* X2hi  = (unsigned short*)alloc((size_t)BATCH * DIM2 * 2);
    unsigned short* X2lo  = (unsigned short*)alloc((size_t)BATCH * DIM2 * 2);
    unsigned short* combhi= (unsigned short*)alloc((size_t)BATCH * DIM * 2);
    unsigned short* comblo= (unsigned short*)alloc((size_t)BATCH * DIM * 2);
    float* img_f  = (float*)alloc((size_t)BATCH * DIM * 4);
    float* txt_f  = (float*)alloc((size_t)BATCH * DIM * 4);
    float* Td     = (float*)alloc((size_t)DIM * DIM2 * 4);
    float* Tc     = (float*)alloc((size_t)DIM * DIM2 * 4);
    float* top2ws = (float*)alloc((size_t)(NQ / 256) * BATCH * 16);
    unsigned short* Bt_hi = (unsigned short*)alloc((size_t)NQ * DIM * 2);
    unsigned short* Bi_hi = (unsigned short*)alloc((size_t)NQ * DIM * 2);

    // 1) prep: qtxt -> bf16 + feature prep + weight transpose
    prep_all<<<dim3(CONVB + 2 * BATCH + 2304), dim3(256), 0, stream>>>(
        img, txt, qtxt, Wd, Wc, Bt_hi,
        img_f, txt_f, X2hi, X2lo, X1hi, X1lo, out2, out3, Td, Tc);

    // 2) retrieval GEMM + top2; convert waves: qimg -> Bi_hi + out2 passthrough
    gemm_big<EPI_TOP2><<<dim3(512), dim3(640), 0, stream>>>(
        X2hi, X2hi + 32, DIM2, Bt_hi, Bt_hi + 32, DIM, DIM, NQ, top2ws, nullptr, BATCH,
        qimg, Bi_hi, out2);

    // 3) global top-4 + exact rescore -> ind_similar + fused gather
    phaseB_kernel<<<dim3(BATCH), dim3(256), 0, stream>>>(
        (const f32x4*)top2ws, NQ / 256, img_f, qtxt, out1, X1hi, X1lo);

    // 4) diff = relu(X1 @ W_diff + b_diff) -> X2[:, 768:] (split)
    gemm_small<64,64,2,2,EPI_BIAS_RELU><<<dim3(DIM / 64, BATCH / 64), dim3(256), 0, stream>>>(
        X1hi, X1lo, DIM2, Td, DIM2, DIM2, bd, X2hi, X2lo, DIM2, DIM);

    // 5) combined = X2 @ W_comb + b_comb -> comb hi/lo
    gemm_small<64,64,2,2,EPI_BIAS><<<dim3(DIM / 64, BATCH / 64), dim3(256), 0, stream>>>(
        X2hi, X2lo, DIM2, Tc, DIM2, DIM2, bc, combhi, comblo, DIM, 0);

    // 6) logits GEMM; convert waves: qtxt -> out3 passthrough
    gemm_big<EPI_SCALE><<<dim3(512), dim3(640), 0, stream>>>(
        combhi, combhi + 32, DIM, Bi_hi, Bi_hi + 32, DIM, DIM, NQ, out0, ls, BATCH,
        qtxt, (unsigned short*)nullptr, out3);
}

// Round 13
// 458.808 us; speedup vs baseline: 2.5710x; 2.0456x over previous
//
#include <hip/hip_runtime.h>
#include <stdint.h>
#include <stddef.h>

#define BATCH 512
#define NQ    65536
#define DIM   768
#define DIM2  1536
#define CONVB 2048

typedef __attribute__((ext_vector_type(4))) float f32x4;
typedef __attribute__((ext_vector_type(4))) unsigned short u16x4;
typedef __attribute__((ext_vector_type(8))) unsigned short u16x8;
typedef __attribute__((ext_vector_type(8))) __bf16 bf16x8;

// ---------- fp32 <-> bf16 (round-to-nearest-even) ----------
static __device__ __forceinline__ unsigned short f2bf(float x){
    unsigned int u = __float_as_uint(x);
    unsigned int r = ((u >> 16) & 1u) + 0x7fffu;
    return (unsigned short)((u + r) >> 16);
}
static __device__ __forceinline__ float bf2f(unsigned short h){
    return __uint_as_float(((unsigned int)h) << 16);
}

// ---------- top-2 tracking ----------
struct T2 { float v1, v2; int i1, i2; };
static __device__ __forceinline__ void t2_add(T2& t, float v, int i){
    if (v > t.v1 || (v == t.v1 && i < t.i1)) { t.v2 = t.v1; t.i2 = t.i1; t.v1 = v; t.i1 = i; }
    else if (v > t.v2 || (v == t.v2 && i < t.i2)) { t.v2 = v; t.i2 = i; }
}
static __device__ __forceinline__ T2 t2_init(){ T2 t; t.v1 = -3.4e38f; t.v2 = -3.4e38f; t.i1 = 0x7fffffff; t.i2 = 0x7fffffff; return t; }

// ---------- prep_all: fused convert(+fp32 passthrough) + feature prep + W transpose ----------
// blocks [0, 2*CONVB): grid-stride conversion qtxt/qimg -> bf16 hi, PLUS exact fp32
//   passthrough into out3/out2 (non-temporal stores: write-once data, keep bf16 bufs in L3).
//   Convert blocks SKIP rows < BATCH for the passthrough (prep role owns them; dispatch
//   order is undefined so the split avoids the race).
// blocks [2*CONVB, +2*BATCH): L2-normalize feats, split hi/lo, seed out2/out3 rows 0..511.
// remaining 2304 blocks: transpose W_diff/W_comb -> [768][1536] fp32.
__global__ __launch_bounds__(256) void prep_all(
    const float* __restrict__ img, const float* __restrict__ txt,
    const float* __restrict__ qtxt, const float* __restrict__ qimg,
    const float* __restrict__ Wd, const float* __restrict__ Wc,
    unsigned short* __restrict__ bthi, unsigned short* __restrict__ bihi,
    float* __restrict__ img_f, float* __restrict__ txt_f,
    unsigned short* __restrict__ X2hi, unsigned short* __restrict__ X2lo,
    unsigned short* __restrict__ X1hi, unsigned short* __restrict__ X1lo,
    float* __restrict__ out2, float* __restrict__ out3,
    float* __restrict__ Td, float* __restrict__ Tc)
{
    __shared__ float tbuf[32][33];
    __shared__ float red[4];
    const int b = blockIdx.x;
    if (b < 2 * CONVB){
        const bool isT = (b < CONVB);
        const float* __restrict__ src = isT ? qtxt : qimg;
        float* __restrict__ dst = isT ? out3 : out2;
        unsigned short* __restrict__ hi = isT ? bthi : bihi;
        const int bb = isT ? b : b - CONVB;
        const size_t skip4 = (size_t)BATCH * DIM / 4;     // rows < BATCH owned by prep role
        const size_t n4 = (size_t)NQ * DIM / 4;
        for (size_t i = (size_t)bb * 256 + threadIdx.x; i < n4; i += (size_t)CONVB * 256){
            f32x4 v = ((const f32x4*)src)[i];
            if (i >= skip4) __builtin_nontemporal_store(v, (f32x4*)dst + i);
            u16x4 h;
            #pragma unroll
            for (int j = 0; j < 4; j++) h[j] = f2bf(v[j]);
            *(u16x4*)(hi + 4*i) = h;
        }
    } else if (b < 2 * CONVB + 2 * BATCH){
        const int b2 = b - 2 * CONVB;
        const bool isimg = (b2 < BATCH);
        const int row = isimg ? b2 : b2 - BATCH;
        const float* src = (isimg ? img : txt) + (size_t)row * DIM;
        float v[3];
        float ss = 0.f;
        #pragma unroll
        for (int i = 0; i < 3; i++){ v[i] = src[threadIdx.x + i*256]; ss += v[i]*v[i]; }
        #pragma unroll
        for (int m = 1; m < 64; m <<= 1) ss += __shfl_xor(ss, m);
        if ((threadIdx.x & 63) == 0) red[threadIdx.x >> 6] = ss;
        __syncthreads();
        float tot = red[0] + red[1] + red[2] + red[3];
        float scale = 1.0f / fmaxf(sqrtf(tot), 1e-12f);
        float* fdst = (isimg ? img_f : txt_f) + (size_t)row * DIM;
        float* odst = (isimg ? out2  : out3 ) + (size_t)row * DIM;
        unsigned short* hid = (isimg ? X2hi : X1hi) + (size_t)row * DIM2;
        unsigned short* lod = (isimg ? X2lo : X1lo) + (size_t)row * DIM2;
        #pragma unroll
        for (int i = 0; i < 3; i++){
            int c = threadIdx.x + i*256;
            float y = v[i] * scale;
            fdst[c] = y; odst[c] = y;
            unsigned short h = f2bf(y);
            hid[c] = h; lod[c] = f2bf(y - bf2f(h));
        }
    } else {
        int t = b - 2 * CONVB - 2 * BATCH;       // 0..2303
        const int z = t / 1152; t -= z * 1152;    // 1152 = 24 * 48
        const int x = t % 24, y = t / 24;
        const float* W = z ? Wc : Wd;
        float*       T = z ? Tc : Td;
        const int x0 = x * 32, y0 = y * 32;
        const int tx = threadIdx.x & 31, ty = threadIdx.x >> 5;
        #pragma unroll
        for (int i = 0; i < 32; i += 8)
            tbuf[ty + i][tx] = W[(size_t)(y0 + ty + i) * DIM + x0 + tx];
        __syncthreads();
        #pragma unroll
        for (int i = 0; i < 32; i += 8)
            T[(size_t)(x0 + ty + i) * DIM2 + y0 + tx] = tbuf[tx][ty + i];
    }
}

#define EPI_TOP2      0
#define EPI_BIAS_RELU 1
#define EPI_BIAS      2
#define EPI_SCALE     3

// ---------- big GEMM: 8-phase schedule, bf16 K64 packing (R8/R10 verified) ----------
template<int EPI>
__global__ __launch_bounds__(512, 2) void gemm_big(
    const unsigned short* __restrict__ Ahi, const unsigned short* __restrict__ Alo, int lda,
    const unsigned short* __restrict__ Bhi, const unsigned short* __restrict__ Blo, int ldb,
    int K, int Nout,
    float* __restrict__ outp, const float* __restrict__ scale_ptr, int Mtot)
{
    constexpr int NT = 512;
    constexpr int KS = 64;
    constexpr int HT = 16384;           // half-tile bytes: 128 rows x 128B
    constexpr int BUF = 4 * HT;         // 64 KiB per K-step
    __shared__ __align__(16) char lds[2 * BUF];   // 128 KiB

    const int tid = threadIdx.x, lane = tid & 63, wid = tid >> 6;
    const int wm = wid >> 2, wn = wid & 3;
    const int lr = lane & 15, lg = lane >> 4;
    const int id = blockIdx.x;
    const int l  = (id & 7) * 64 + (id >> 3);
    const int nb = l >> 1, mb = l & 1;
    const int m0 = mb * 256, n0 = nb * 256;

    f32x4 acc[8][4] = {};

    auto stageHT = [&](int T){
        int kind = T & 3, ks = T >> 2;
        char* base = lds + (ks & 1) * BUF + kind * HT;
        const unsigned short* hi = (kind < 2) ? Ahi : Bhi;
        const unsigned short* lo = (kind < 2) ? Alo : Blo;
        int ld = (kind < 2) ? lda : ldb;
        int r0 = ((kind < 2) ? m0 : n0) + (kind & 1) * 128;
        int k0 = ks * KS;
        #pragma unroll
        for (int r = 0; r < 2; r++){
            int G = r * NT + tid, row = G >> 3, slot = G & 7, s0 = slot ^ (row & 7);
            const unsigned short* s = ((s0 < 4) ? hi : lo) + (size_t)(r0 + row) * ld + k0 + (s0 & 3) * 8;
            __builtin_amdgcn_global_load_lds(
                (const __attribute__((address_space(1))) void*)s,
                (__attribute__((address_space(3))) void*)(base + (r * NT + (tid & ~63)) * 16), 16, 0, 0);
        }
    };

    const int xh = (lg ^ (lr & 7)) << 4;
    const int xl = ((4 + lg) ^ (lr & 7)) << 4;

    const int nk = K / KS;   // 12
    stageHT(0); stageHT(1); stageHT(2); stageHT(3);
    if (nk > 1){
        stageHT(6); stageHT(7);
        asm volatile("s_waitcnt vmcnt(4)" ::: "memory");
    } else {
        asm volatile("s_waitcnt vmcnt(0)" ::: "memory");
    }
    __syncthreads();

    for (int kt = 0; kt < nk; kt++){
        const char* Ab = lds + (kt & 1) * BUF;
        const char* Bb = Ab + 2 * HT;
        bf16x8 bh[4], bl[4];
        #pragma unroll
        for (int q = 0; q < 4; q++){
            if (q < 2){ if (kt + 1 < nk) stageHT(4 * (kt + 1) + q); }
            else      { if (kt + 2 < nk) stageHT(4 * (kt + 2) + q); }
            if (q == 0){
                #pragma unroll
                for (int nf = 0; nf < 4; nf++){
                    const char* rp = Bb + (wn * 64 + nf * 16 + lr) * 128;
                    bh[nf] = *(const bf16x8*)(rp + xh);
                    bl[nf] = *(const bf16x8*)(rp + xl);
                }
            }
            const char* rp0 = Ab + (wm * 128 + q * 32 + lr) * 128;
            const char* rp1 = rp0 + 16 * 128;
            bf16x8 a0h = *(const bf16x8*)(rp0 + xh);
            bf16x8 a0l = *(const bf16x8*)(rp0 + xl);
            bf16x8 a1h = *(const bf16x8*)(rp1 + xh);
            bf16x8 a1l = *(const bf16x8*)(rp1 + xl);
            asm volatile("s_barrier" ::: "memory");
            asm volatile("s_waitcnt lgkmcnt(0)" ::: "memory");
            __builtin_amdgcn_sched_barrier(0);
            __builtin_amdgcn_s_setprio(1);
            #pragma unroll
            for (int nf = 0; nf < 4; nf++)
                acc[2*q  ][nf] = __builtin_amdgcn_mfma_f32_16x16x32_bf16(a0h, bh[nf], acc[2*q  ][nf], 0, 0, 0);
            #pragma unroll
            for (int nf = 0; nf < 4; nf++)
                acc[2*q+1][nf] = __builtin_amdgcn_mfma_f32_16x16x32_bf16(a1h, bh[nf], acc[2*q+1][nf], 0, 0, 0);
            #pragma unroll
            for (int nf = 0; nf < 4; nf++)
                acc[2*q  ][nf] = __builtin_amdgcn_mfma_f32_16x16x32_bf16(a0l, bl[nf], acc[2*q  ][nf], 0, 0, 0);
            #pragma unroll
            for (int nf = 0; nf < 4; nf++)
                acc[2*q+1][nf] = __builtin_amdgcn_mfma_f32_16x16x32_bf16(a1l, bl[nf], acc[2*q+1][nf], 0, 0, 0);
            __builtin_amdgcn_s_setprio(0);
            if (q == 3){
                if (kt < nk - 2)       asm volatile("s_waitcnt vmcnt(4)" ::: "memory");
                else if (kt == nk - 2) asm volatile("s_waitcnt vmcnt(0)" ::: "memory");
            }
            asm volatile("s_barrier" ::: "memory");
        }
    }

    if constexpr (EPI == EPI_TOP2){
        T2* t2l = (T2*)lds;   // [4][256]
        #pragma unroll
        for (int mf = 0; mf < 8; mf++){
            #pragma unroll
            for (int r = 0; r < 4; r++){
                T2 t = t2_init();
                #pragma unroll
                for (int nf = 0; nf < 4; nf++){
                    int gc = n0 + wn * 64 + nf * 16 + lr;
                    t2_add(t, acc[mf][nf][r], gc);
                }
                #pragma unroll
                for (int m = 1; m < 16; m <<= 1){
                    float ov1 = __shfl_xor(t.v1, m), ov2 = __shfl_xor(t.v2, m);
                    int   oi1 = __shfl_xor(t.i1, m), oi2 = __shfl_xor(t.i2, m);
                    t2_add(t, ov1, oi1); t2_add(t, ov2, oi2);
                }
                if (lr == 0){
                    int rowit = wm * 128 + mf * 16 + lg * 4 + r;
                    t2l[wn * 256 + rowit] = t;
                }
            }
        }
        __syncthreads();
        if (tid < 256){
            T2 t = t2l[tid];
            #pragma unroll
            for (int w = 1; w < 4; w++){
                T2 o = t2l[w * 256 + tid];
                t2_add(t, o.v1, o.i1); t2_add(t, o.v2, o.i2);
            }
            f32x4 pk; pk[0] = t.v1; pk[1] = __int_as_float(t.i1); pk[2] = t.v2; pk[3] = __int_as_float(t.i2);
            ((f32x4*)outp)[(size_t)nb * Mtot + (m0 + tid)] = pk;
        }
    } else if constexpr (EPI == EPI_SCALE){
        float sc = scale_ptr[0];
        #pragma unroll
        for (int mf = 0; mf < 8; mf++)
        #pragma unroll
        for (int nf = 0; nf < 4; nf++)
        #pragma unroll
        for (int r = 0; r < 4; r++){
            int grow = m0 + wm * 128 + mf * 16 + lg * 4 + r;
            int gcol = n0 + wn * 64 + nf * 16 + lr;
            outp[(size_t)grow * Nout + gcol] = acc[mf][nf][r] * sc;
        }
    }
}

// ---------- small GEMM (MLP layers): A bf16 hi/lo, B fp32 with in-kernel convert ----------
template<int BM,int BN,int WGM,int WGN,int EPI>
__global__ __launch_bounds__(WGM*WGN*64) void gemm_small(
    const unsigned short* __restrict__ Ahi, const unsigned short* __restrict__ Alo, int lda,
    const float* __restrict__ B, int ldb, int K,
    const float* __restrict__ bias,
    unsigned short* __restrict__ dsthi, unsigned short* __restrict__ dstlo, int ldd, int dstoff)
{
    constexpr int WM = BM / WGM, WN = BN / WGN;
    constexpr int MF = WM / 16, NF = WN / 16;
    constexpr int NT = WGM * WGN * 64;
    constexpr int ABYTES = BM * 128;
    constexpr int BBYTES = BN * 128;
    constexpr int BUF = ABYTES + BBYTES;
    static_assert(BN * 4 == NT, "");
    static_assert((BM * 8) % NT == 0, "");

    __shared__ __align__(16) char lds[2 * BUF];

    const int tid  = threadIdx.x;
    const int wid  = tid >> 6, lane = tid & 63;
    const int wm   = wid / WGN, wn = wid % WGN;
    const int lr   = lane & 15, lg = lane >> 4;
    const int nb   = blockIdx.x, mb = blockIdx.y;
    const int m0   = mb * BM, n0 = nb * BN;

    f32x4 acc[MF][NF] = {};
    f32x4 breg0, breg1;

    auto stageA = [&](int buf, int k0){
        char* base = lds + buf * BUF;
        constexpr int RA = BM * 8 / NT;
        #pragma unroll
        for (int r = 0; r < RA; r++){
            int G = r * NT + tid;
            int row = G >> 3, slot = G & 7;
            int s0 = slot ^ (row & 7);
            const unsigned short* src = ((s0 < 4) ? Ahi : Alo)
                + (size_t)(m0 + row) * lda + (k0 + (s0 & 3) * 8);
            char* ldst = base + r * NT * 16 + (tid & ~63) * 16;
            __builtin_amdgcn_global_load_lds(
                (const __attribute__((address_space(1))) void*)src,
                (__attribute__((address_space(3))) void*)ldst, 16, 0, 0);
        }
    };
    auto loadB = [&](int kt){
        int k0 = kt * 32;
        int row = tid >> 2, quad = tid & 3;
        const float* bp = B + (size_t)(n0 + row) * ldb + k0 + quad * 8;
        breg0 = *(const f32x4*)bp;
        breg1 = *(const f32x4*)(bp + 4);
    };
    auto writeB = [&](int buf){
        char* base = lds + buf * BUF + ABYTES;
        int row = tid >> 2, quad = tid & 3;
        u16x8 h8, l8;
        #pragma unroll
        for (int j = 0; j < 8; j++){
            float x = (j < 4) ? breg0[j] : breg1[j - 4];
            unsigned short h = f2bf(x);
            h8[j] = h; l8[j] = f2bf(x - bf2f(h));
        }
        int sh = quad ^ (row & 7), sl = (4 + quad) ^ (row & 7);
        *(u16x8*)(base + row * 128 + sh * 16) = h8;
        *(u16x8*)(base + row * 128 + sl * 16) = l8;
    };
    auto compute = [&](int buf){
        const char* Ab = lds + buf * BUF;
        const char* Bb = Ab + ABYTES;
        bf16x8 ah[MF], al[MF], bh[NF], bl[NF];
        #pragma unroll
        for (int mf = 0; mf < MF; mf++){
            int row = wm * WM + mf * 16 + lr;
            const char* rp = Ab + row * 128;
            ah[mf] = *(const bf16x8*)(rp + ((lg ^ (row & 7)) << 4));
            al[mf] = *(const bf16x8*)(rp + (((4 + lg) ^ (row & 7)) << 4));
        }
        #pragma unroll
        for (int nf = 0; nf < NF; nf++){
            int row = wn * WN + nf * 16 + lr;
            const char* rp = Bb + row * 128;
            bh[nf] = *(const bf16x8*)(rp + ((lg ^ (row & 7)) << 4));
            bl[nf] = *(const bf16x8*)(rp + (((4 + lg) ^ (row & 7)) << 4));
        }
        #pragma unroll
        for (int mf = 0; mf < MF; mf++)
        #pragma unroll
        for (int nf = 0; nf < NF; nf++){
            acc[mf][nf] = __builtin_amdgcn_mfma_f32_16x16x32_bf16(ah[mf], bh[nf], acc[mf][nf], 0, 0, 0);
            acc[mf][nf] = __builtin_amdgcn_mfma_f32_16x16x32_bf16(al[mf], bh[nf], acc[mf][nf], 0, 0, 0);
            acc[mf][nf] = __builtin_amdgcn_mfma_f32_16x16x32_bf16(ah[mf], bl[nf], acc[mf][nf], 0, 0, 0);
        }
    };

    stageA(0, 0); loadB(0); writeB(0);
    __syncthreads();
    const int nk = K / 32;
    int cur = 0;
    for (int kt = 0; kt < nk; kt++){
        if (kt + 1 < nk){ stageA(cur ^ 1, (kt + 1) * 32); loadB(kt + 1); }
        compute(cur);
        if (kt + 1 < nk){ writeB(cur ^ 1); }
        __syncthreads();
        cur ^= 1;
    }

    #pragma unroll
    for (int mf = 0; mf < MF; mf++)
    #pragma unroll
    for (int nf = 0; nf < NF; nf++)
    #pragma unroll
    for (int r = 0; r < 4; r++){
        int grow = m0 + wm * WM + mf * 16 + lg * 4 + r;
        int gcol = n0 + wn * WN + nf * 16 + lr;
        float c = acc[mf][nf][r] + bias[gcol];
        if (EPI == EPI_BIAS_RELU) c = fmaxf(c, 0.f);
        unsigned short h = f2bf(c);
        size_t o = (size_t)grow * ldd + dstoff + gcol;
        dsthi[o] = h;
        dstlo[o] = f2bf(c - bf2f(h));
    }
}

// ---------- phase B: global top-4 + exact fp32 rescore + fused gather ----------
__global__ __launch_bounds__(256) void phaseB_kernel(
    const f32x4* __restrict__ top2ws, int ntiles,
    const float* __restrict__ img_f, const float* __restrict__ qtxt,
    float* __restrict__ out_ind,
    unsigned short* __restrict__ X1hi, unsigned short* __restrict__ X1lo)
{
    __shared__ float vals[512];
    __shared__ int   inds[512];
    __shared__ float red[4];
    __shared__ int   redi[4];
    __shared__ int   cands[4];
    __shared__ float cscore[4];
    __shared__ int   finali;
    const int row = blockIdx.x, tid = threadIdx.x;

    if (tid < ntiles){
        f32x4 e = top2ws[(size_t)tid * BATCH + row];
        vals[2*tid]   = e[0]; inds[2*tid]   = __float_as_int(e[1]);
        vals[2*tid+1] = e[2]; inds[2*tid+1] = __float_as_int(e[3]);
    }
    __syncthreads();

    for (int it = 0; it < 4; it++){
        float v = vals[tid]; int i = inds[tid];
        {
            float v2 = vals[tid+256]; int i2 = inds[tid+256];
            if (v2 > v || (v2 == v && i2 < i)){ v = v2; i = i2; }
        }
        #pragma unroll
        for (int m = 1; m < 64; m <<= 1){
            float ov = __shfl_xor(v, m); int oi = __shfl_xor(i, m);
            if (ov > v || (ov == v && oi < i)){ v = ov; i = oi; }
        }
        if ((tid & 63) == 0){ red[tid>>6] = v; redi[tid>>6] = i; }
        __syncthreads();
        if (tid == 0){
            float bv = red[0]; int bi = redi[0];
            #pragma unroll
            for (int w = 1; w < 4; w++)
                if (red[w] > bv || (red[w] == bv && redi[w] < bi)){ bv = red[w]; bi = redi[w]; }
            cands[it] = bi;
        }
        __syncthreads();
        if (inds[tid]     == cands[it]) vals[tid]     = -3.4e38f;
        if (inds[tid+256] == cands[it]) vals[tid+256] = -3.4e38f;
        __syncthreads();
    }

    const float* a = img_f + (size_t)row * DIM;
    float a0 = a[tid], a1 = a[tid + 256], a2 = a[tid + 512];
    for (int c = 0; c < 4; c++){
        const float* bp = qtxt + (size_t)cands[c] * DIM;
        float s = a0 * bp[tid] + a1 * bp[tid + 256] + a2 * bp[tid + 512];
        #pragma unroll
        for (int m = 1; m < 64; m <<= 1) s += __shfl_xor(s, m);
        if ((tid & 63) == 0) red[tid>>6] = s;
        __syncthreads();
        if (tid == 0) cscore[c] = red[0] + red[1] + red[2] + red[3];
        __syncthreads();
    }
    if (tid == 0){
        float bs = cscore[0]; int bi = cands[0];
        #pragma unroll
        for (int c = 1; c < 4; c++)
            if (cscore[c] > bs || (cscore[c] == bs && cands[c] < bi)){ bs = cscore[c]; bi = cands[c]; }
        out_ind[row] = (float)bi;
        finali = bi;
    }
    __syncthreads();

    const float* src = qtxt + (size_t)finali * DIM;
    for (int c = tid; c < DIM; c += 256){
        float x = src[c];
        unsigned short h = f2bf(x);
        X1hi[(size_t)row * DIM2 + DIM + c] = h;
        X1lo[(size_t)row * DIM2 + DIM + c] = f2bf(x - bf2f(h));
    }
}

extern "C" void kernel_launch(void* const* d_in, const int* in_sizes, int n_in,
                              void* d_out, int out_size, void* d_ws, size_t ws_size,
                              hipStream_t stream)
{
    (void)in_sizes; (void)n_in; (void)out_size; (void)ws_size;
    const float* img  = (const float*)d_in[0];
    const float* txt  = (const float*)d_in[1];
    const float* qimg = (const float*)d_in[2];
    const float* qtxt = (const float*)d_in[3];
    const float* Wd   = (const float*)d_in[4];
    const float* bd   = (const float*)d_in[5];
    const float* Wc   = (const float*)d_in[6];
    const float* bc   = (const float*)d_in[7];
    const float* ls   = (const float*)d_in[8];

    float* out0 = (float*)d_out;                    // logits [512][65536]
    float* out1 = out0 + (size_t)BATCH * NQ;        // ind_similar [512] (as f32)
    float* out2 = out1 + BATCH;                     // new_queue_img [65536][768]
    float* out3 = out2 + (size_t)NQ * DIM;          // new_queue_txt [65536][768]

    char* w = (char*)d_ws;
    auto alloc = [&](size_t bytes){ char* p = w; w += (bytes + 255) & ~(size_t)255; return p; };
    unsigned short* X1hi  = (unsigned short*)alloc((size_t)BATCH * DIM2 * 2);
    unsigned short* X1lo  = (unsigned short*)alloc((size_t)BATCH * DIM2 * 2);
    unsigned short* X2hi  = (unsigned short*)alloc((size_t)BATCH * DIM2 * 2);
    unsigned short* X2lo  = (unsigned short*)alloc((size_t)BATCH * DIM2 * 2);
    unsigned short* combhi= (unsigned short*)alloc((size_t)BATCH * DIM * 2);
    unsigned short* comblo= (unsigned short*)alloc((size_t)BATCH * DIM * 2);
    float* img_f  = (float*)alloc((size_t)BATCH * DIM * 4);
    float* txt_f  = (float*)alloc((size_t)BATCH * DIM * 4);
    float* Td     = (float*)alloc((size_t)DIM * DIM2 * 4);
    float* Tc     = (float*)alloc((size_t)DIM * DIM2 * 4);
    float* top2ws = (float*)alloc((size_t)(NQ / 256) * BATCH * 16);
    unsigned short* Bt_hi = (unsigned short*)alloc((size_t)NQ * DIM * 2);
    unsigned short* Bi_hi = (unsigned short*)alloc((size_t)NQ * DIM * 2);

    // 1) fused: queue->bf16 convert + fp32 passthrough + feature prep + weight transpose
    prep_all<<<dim3(2 * CONVB + 2 * BATCH + 2304), dim3(256), 0, stream>>>(
        img, txt, qtxt, qimg, Wd, Wc, Bt_hi, Bi_hi,
        img_f, txt_f, X2hi, X2lo, X1hi, X1lo, out2, out3, Td, Tc);

    // 2) retrieval GEMM (bf16 hi-only, K64 packing) + per-tile top2  [512 blocks]
    gemm_big<EPI_TOP2><<<dim3(512), dim3(512), 0, stream>>>(
        X2hi, X2hi + 32, DIM2, Bt_hi, Bt_hi + 32, DIM, DIM, NQ, top2ws, nullptr, BATCH);

    // 3) global top-4 + exact rescore -> ind_similar + fused gather
    phaseB_kernel<<<dim3(BATCH), dim3(256), 0, stream>>>(
        (const f32x4*)top2ws, NQ / 256, img_f, qtxt, out1, X1hi, X1lo);

    // 4) diff = relu(X1 @ W_diff + b_diff) -> X2[:, 768:] (split)
    gemm_small<64,64,2,2,EPI_BIAS_RELU><<<dim3(DIM / 64, BATCH / 64), dim3(256), 0, stream>>>(
        X1hi, X1lo, DIM2, Td, DIM2, DIM2, bd, X2hi, X2lo, DIM2, DIM);

    // 5) combined = X2 @ W_comb + b_comb -> comb hi/lo
    gemm_small<64,64,2,2,EPI_BIAS><<<dim3(DIM / 64, BATCH / 64), dim3(256), 0, stream>>>(
        X2hi, X2lo, DIM2, Tc, DIM2, DIM2, bc, combhi, comblo, DIM, 0);

    // 6) logits = scale * combined @ queue_img^T (K64 hi-only, 8-phase)  [512 blocks]
    gemm_big<EPI_SCALE><<<dim3(512), dim3(512), 0, stream>>>(
        combhi, combhi + 32, DIM, Bi_hi, Bi_hi + 32, DIM, DIM, NQ, out0, ls, BATCH);
}